// Round 3
// baseline (654.861 us; speedup 1.0000x reference)
//
#include <hip/hip_runtime.h>
#include <hip/hip_cooperative_groups.h>
#include <math.h>

namespace cg = cooperative_groups;

#define N_CELLS 1024
#define HID     256
#define IN_DIM  256
#define NOISE_DIM 32
#define OUT_DIM 256
#define N_LOOP  32
#define FLAT    (N_CELLS*HID)   // 262144

__device__ __forceinline__ float wave_reduce64(float v) {
    #pragma unroll
    for (int m = 32; m; m >>= 1) v += __shfl_xor(v, m);
    return v;
}
__device__ __forceinline__ float wave_reduce32(float v) {
    #pragma unroll
    for (int m = 16; m; m >>= 1) v += __shfl_xor(v, m);
    return v;
}

// ============ COOP kernel 1: generator head (h1 then h2) ============
__global__ void __launch_bounds__(256)
k_gen_head(const float* __restrict__ x, const float* __restrict__ noise,
           const float* __restrict__ W1, const float* __restrict__ b1,
           const float* __restrict__ W2, const float* __restrict__ b2,
           float* __restrict__ h1, float* __restrict__ h2) {
    cg::grid_group grid = cg::this_grid();
    __shared__ __align__(16) float gi[288];
    int t = threadIdx.x, l = t & 63, w = t >> 6;
    int wid = blockIdx.x * 4 + w;
    if (blockIdx.x < 64) {                      // h1: 256 rows x 288
        gi[t] = x[t];
        if (t < 32) gi[256 + t] = noise[t];
        __syncthreads();
        int j = wid;
        const float4* wr = (const float4*)(W1 + j * 288);
        const float4* g4 = (const float4*)gi;
        float4 a = wr[l], v = g4[l];
        float acc = a.x*v.x + a.y*v.y + a.z*v.z + a.w*v.w;
        if (l < 8) {
            float4 a2 = wr[64 + l], v2 = g4[64 + l];
            acc += a2.x*v2.x + a2.y*v2.y + a2.z*v2.z + a2.w*v2.w;
        }
        acc = wave_reduce64(acc);
        if (l == 0) h1[j] = fmaxf(acc + b1[j], 0.f);
    }
    grid.sync();
    {                                           // h2: 512 rows x 256
        int j = wid;
        float4 a = ((const float4*)(W2 + j * 256))[l];
        float4 v = ((const float4*)h1)[l];
        float acc = a.x*v.x + a.y*v.y + a.z*v.z + a.w*v.w;
        acc = wave_reduce64(acc);
        if (l == 0) h2[j] = fmaxf(acc + b2[j], 0.f);
    }
}

// ============ gen_states = W3 . h2 + b3 (wave per row) ============
__global__ void k_gen_big(const float* __restrict__ W3, const float* __restrict__ b3,
                          const float* __restrict__ h2, float* __restrict__ gs) {
    int lane = threadIdx.x & 63;
    int row  = blockIdx.x * (blockDim.x >> 6) + (threadIdx.x >> 6);
    const float4* h24 = (const float4*)h2;
    float4 ha = h24[lane], hb = h24[64 + lane];
    const float4* w4 = (const float4*)(W3 + (size_t)row * 512);
    float4 wa = w4[lane], wb = w4[64 + lane];
    float acc = wa.x*ha.x + wa.y*ha.y + wa.z*ha.z + wa.w*ha.w
              + wb.x*hb.x + wb.y*hb.y + wb.z*hb.z + wb.w*hb.w;
    acc = wave_reduce64(acc);
    if (lane == 0) gs[row] = acc + b3[row];
}

// ============ COOP kernel 2: the entire small-op chain ============
__global__ void __launch_bounds__(256)
k_mega(const float* __restrict__ gs, const float* __restrict__ ch,
       const int* __restrict__ step, const float* __restrict__ x,
       const float* __restrict__ eaW1, const float* __restrict__ eab1,
       const float* __restrict__ eaW2, const float* __restrict__ eab2,
       const float* __restrict__ egW1, const float* __restrict__ egb1,
       const float* __restrict__ egW2, const float* __restrict__ egb2,
       const float* __restrict__ Wih, const float* __restrict__ bih,
       const float* __restrict__ Whh, const float* __restrict__ bhh,
       float* __restrict__ fmean, float* __restrict__ synced,
       float* __restrict__ ncn, float* __restrict__ comb,
       float* __restrict__ h1ag, float* __restrict__ outputs,
       float* __restrict__ tensions, float* __restrict__ rz,
       float* __restrict__ inb, float* __restrict__ hnb,
       float* __restrict__ out) {
    cg::grid_group grid = cg::this_grid();
    int b = blockIdx.x, t = threadIdx.x, l = t & 63, w = t >> 6;
    __shared__ float s0[4][64];
    __shared__ float red[256];
    __shared__ float sw[32];
    __shared__ float sts[32];

    // ---- P0: per-faction column means (blocks 0..31) ----
    if (b < 32) {
        int f = b >> 2, q = b & 3;
        int c = q * 64 + l, rg = w;
        const float* base = gs + (size_t)(f * 128 + rg * 32) * 256 + c;
        float s = 0.f;
        for (int i = 0; i < 32; ++i) s += base[(size_t)i * 256];
        s0[rg][l] = s;
        __syncthreads();
        if (t < 64)
            fmean[f * 256 + q * 64 + t] =
                (s0[0][t] + s0[1][t] + s0[2][t] + s0[3][t]) * (1.f / 128.f);
    }
    grid.sync();

    // ---- P1: synced / ncn / comb (2 cells per block) ----
    {
        int d = t;
        float gm = 0.f;
        #pragma unroll
        for (int k = 0; k < 8; ++k) gm += fmean[k * 256 + d];
        gm *= 0.125f;
        bool deb = (*step > 5);
        #pragma unroll
        for (int cc = 0; cc < 2; ++cc) {
            int c = b * 2 + cc;
            int f = c >> 7;
            float fm = fmean[f * 256 + d];
            float v = 0.85f * gs[c * 256 + d] + 0.15f * fm;
            if (((c & 127) < 32) && deb) v = 0.85f * v + 0.15f * gm;
            synced[c * 256 + d] = v;
            ncn[c * 256 + d] = 0.7f * v + 0.3f * ch[c * 256 + d];
            if (c < N_LOOP) { comb[c * 512 + d] = x[d]; comb[c * 512 + 256 + d] = v; }
        }
    }
    grid.sync();

    // ---- P2: evaluator layer 1 (blocks 0..63, wave-per-row, 256 rows x 512) ----
    if (b < 64) {
        int j = b * 4 + w;
        const float* W = (j < 128) ? (eaW1 + j * 512) : (egW1 + (j - 128) * 512);
        float bias = (j < 128) ? eab1[j] : egb1[j - 128];
        const float4* w4 = (const float4*)W;
        float4 wa = w4[l], wb = w4[64 + l];
        for (int i = 0; i < N_LOOP; ++i) {
            const float4* ci = (const float4*)(comb + i * 512);
            float4 va = ci[l], vb = ci[64 + l];
            float acc = wa.x*va.x + wa.y*va.y + wa.z*va.z + wa.w*va.w
                      + wb.x*vb.x + wb.y*vb.y + wb.z*vb.z + wb.w*vb.w;
            acc = wave_reduce64(acc);
            if (l == 0) h1ag[i * 256 + j] = fmaxf(acc + bias, 0.f);
        }
    }
    grid.sync();

    // ---- P3: evaluator layer 2, outputs = a - g (blocks 0..63, wave-per-neuron) ----
    if (b < 64) {
        int tr = b * 4 + w;
        bool lo = (l < 32);
        int sl = l & 31;
        float4 wv = lo ? ((const float4*)(eaW2 + tr * 128))[sl]
                       : ((const float4*)(egW2 + tr * 128))[sl];
        float bias = eab2[tr] - egb2[tr];
        for (int i = 0; i < N_LOOP; ++i) {
            const float* hrow = h1ag + i * 256 + (lo ? 0 : 128);
            float4 v = *(const float4*)(hrow + sl * 4);
            float d_ = wv.x*v.x + wv.y*v.y + wv.z*v.z + wv.w*v.w;
            float acc = lo ? d_ : -d_;
            acc = wave_reduce64(acc);
            if (l == 0) outputs[i * 256 + tr] = acc + bias;
        }
    }
    grid.sync();

    // ---- P4: tensions (blocks 0..31) ----
    if (b < 32) {
        float o = outputs[b * 256 + t];
        red[t] = o * o;
        __syncthreads();
        for (int m = 128; m; m >>= 1) { if (t < m) red[t] += red[t + m]; __syncthreads(); }
        if (t == 0) tensions[b] = red[0] * (1.f / 256.f);
    }
    grid.sync();

    // ---- P5: GRU matvecs (blocks 0..191, wave-per-row, 768 rows) ----
    if (b < 192) {
        int u = b * 4 + w;
        const float* wr = Wih + (size_t)u * 257;
        float w0 = wr[4*l], w1 = wr[4*l+1], w2 = wr[4*l+2], w3 = wr[4*l+3];
        float wlast = wr[256];
        float4 wh = ((const float4*)(Whh + (size_t)u * 256))[l];
        float bg = bih[u], bh = bhh[u];
        bool isN = (u >= 512);
        for (int i = 0; i < N_LOOP; ++i) {
            const float* oi = outputs + i * 256 + 4 * l;
            const float* hi = synced + i * 256 + 4 * l;
            float ga = w0*oi[0] + w1*oi[1] + w2*oi[2] + w3*oi[3];
            float hh = wh.x*hi[0] + wh.y*hi[1] + wh.z*hi[2] + wh.w*hi[3];
            if (!isN) {
                float s = wave_reduce64(ga + hh);
                if (l == 0) rz[i * 512 + u] = s + bg + bh + wlast * tensions[i];
            } else {
                float sg2 = wave_reduce64(ga);
                float sh  = wave_reduce64(hh);
                if (l == 0) {
                    inb[i * 256 + (u - 512)] = sg2 + bg + wlast * tensions[i];
                    hnb[i * 256 + (u - 512)] = sh + bh;
                }
            }
        }
    }
    grid.sync();

    // ---- P6: GRU finish (blocks 0..31) + softmax combine (block 32) ----
    if (b < 32) {
        int i = b, d = t;
        float r = 1.f / (1.f + expf(-rz[i * 512 + d]));
        float z = 1.f / (1.f + expf(-rz[i * 512 + 256 + d]));
        float nc = tanhf(inb[i * 256 + d] + r * hnb[i * 256 + d]);
        float H = synced[i * 256 + d];
        out[259 + i * 256 + d] = (1.f - z) * nc + z * H;
    } else if (b == 32) {
        if (t < 32) sts[t] = tensions[t];
        __syncthreads();
        if (t == 0) {
            float mx = sts[0];
            for (int i2 = 1; i2 < 32; ++i2) mx = fmaxf(mx, sts[i2]);
            float s = 0.f, mean = 0.f;
            for (int i2 = 0; i2 < 32; ++i2) { float e = expf(sts[i2] - mx); sw[i2] = e; s += e; mean += sts[i2]; }
            float inv = 1.f / s;
            for (int i2 = 0; i2 < 32; ++i2) sw[i2] *= inv;
            out[256] = mean * (1.f / 32.f);
        }
        __syncthreads();
        float c = 0.f;
        for (int i2 = 0; i2 < 32; ++i2) c += sw[i2] * outputs[i2 * 256 + t];
        out[t] = c;
    }
}

// ============ fused disc layer-1 for real+fake ============
__global__ void k_disc1(const float* __restrict__ W1, const float* __restrict__ b1,
                        const float* __restrict__ real, const float* __restrict__ fake,
                        float* __restrict__ d1r, float* __restrict__ d1f) {
    __shared__ float sR[16];
    __shared__ float sF[16];
    int row = blockIdx.x, t = threadIdx.x, l = t & 63, w = t >> 6;
    const float4* w4 = (const float4*)(W1 + (size_t)row * FLAT);
    const float4* r4 = (const float4*)real;
    const float4* f4 = (const float4*)fake;
    float aR = 0.f, aF = 0.f;
    for (int i = t; i < FLAT / 4; i += 1024) {
        float4 ww = w4[i], r = r4[i], f = f4[i];
        aR += ww.x*r.x + ww.y*r.y + ww.z*r.z + ww.w*r.w;
        aF += ww.x*f.x + ww.y*f.y + ww.z*f.z + ww.w*f.w;
    }
    aR = wave_reduce64(aR);
    aF = wave_reduce64(aF);
    if (l == 0) { sR[w] = aR; sF[w] = aF; }
    __syncthreads();
    if (t < 16) {
        float r = sR[t], f = sF[t];
        #pragma unroll
        for (int m = 8; m; m >>= 1) { r += __shfl_xor(r, m); f += __shfl_xor(f, m); }
        if (t == 0) { d1r[row] = r + b1[row]; d1f[row] = f + b1[row]; }
    }
}

// ============ disc layers 2+3 (block 0 = real, block 1 = fake) ============
__global__ void k_disc_tail(const float* __restrict__ W2, const float* __restrict__ b2,
                            const float* __restrict__ W3, const float* __restrict__ b3,
                            const float* __restrict__ d1r, const float* __restrict__ d1f,
                            float* __restrict__ out) {
    __shared__ __align__(16) float lv[512];
    __shared__ float l2[256];
    __shared__ float red[256];
    int b = blockIdx.x, t = threadIdx.x;
    const float* d1 = b ? d1f : d1r;
    for (int j = t; j < 512; j += 256) { float v = d1[j]; lv[j] = v > 0.f ? v : 0.2f * v; }
    __syncthreads();
    {
        float acc = b2[t];
        const float4* wr = (const float4*)(W2 + t * 512);
        const float4* l4 = (const float4*)lv;
        for (int k = 0; k < 128; ++k) {
            float4 w = wr[k], v = l4[k];
            acc += w.x*v.x + w.y*v.y + w.z*v.z + w.w*v.w;
        }
        l2[t] = acc > 0.f ? acc : 0.2f * acc;
    }
    __syncthreads();
    red[t] = l2[t] * W3[t];
    __syncthreads();
    for (int m = 128; m; m >>= 1) { if (t < m) red[t] += red[t + m]; __syncthreads(); }
    if (t == 0) { float v = red[0] + b3[0]; out[257 + b] = 1.f / (1.f + expf(-v)); }
}

// ==================== FALLBACK (non-cooperative) kernels ====================
__global__ void k_gen_h1(const float* __restrict__ x, const float* __restrict__ noise,
                         const float* __restrict__ W1, const float* __restrict__ b1,
                         float* __restrict__ h1) {
    __shared__ __align__(16) float gi[288];
    int t = threadIdx.x, l = t & 63, w = t >> 6;
    gi[t] = x[t];
    if (t < 32) gi[256 + t] = noise[t];
    __syncthreads();
    int j = blockIdx.x * 4 + w;
    const float4* wr = (const float4*)(W1 + j * 288);
    const float4* g4 = (const float4*)gi;
    float4 a = wr[l], v = g4[l];
    float acc = a.x*v.x + a.y*v.y + a.z*v.z + a.w*v.w;
    if (l < 8) {
        float4 a2 = wr[64 + l], v2 = g4[64 + l];
        acc += a2.x*v2.x + a2.y*v2.y + a2.z*v2.z + a2.w*v2.w;
    }
    acc = wave_reduce64(acc);
    if (l == 0) h1[j] = fmaxf(acc + b1[j], 0.f);
}

__global__ void k_gen_h2(const float* __restrict__ h1, const float* __restrict__ W2,
                         const float* __restrict__ b2, float* __restrict__ h2) {
    int t = threadIdx.x, l = t & 63, w = t >> 6;
    int j = blockIdx.x * 4 + w;
    float4 a = ((const float4*)(W2 + j * 256))[l];
    float4 v = ((const float4*)h1)[l];
    float acc = a.x*v.x + a.y*v.y + a.z*v.z + a.w*v.w;
    acc = wave_reduce64(acc);
    if (l == 0) h2[j] = fmaxf(acc + b2[j], 0.f);
}

__global__ void k_fmean(const float* __restrict__ gs, float* __restrict__ fmean) {
    __shared__ float part[4][64];
    int b = blockIdx.x, t = threadIdx.x;
    int f = b >> 2, q = b & 3;
    int c = q * 64 + (t & 63), rg = t >> 6;
    const float* base = gs + (size_t)(f * 128 + rg * 32) * 256 + c;
    float s = 0.f;
    for (int i = 0; i < 32; ++i) s += base[(size_t)i * 256];
    part[rg][t & 63] = s;
    __syncthreads();
    if (t < 64) {
        float v = part[0][t] + part[1][t] + part[2][t] + part[3][t];
        fmean[f * 256 + q * 64 + t] = v * (1.f / 128.f);
    }
}

__global__ void k_sync(const float* __restrict__ gs, const float* __restrict__ fmean,
                       const float* __restrict__ ch, const int* __restrict__ step,
                       const float* __restrict__ x,
                       float* __restrict__ synced, float* __restrict__ ncn,
                       float* __restrict__ comb) {
    int c = blockIdx.x, d = threadIdx.x;
    int f = c >> 7;
    float gm = 0.f;
    #pragma unroll
    for (int k = 0; k < 8; ++k) gm += fmean[k * 256 + d];
    gm *= 0.125f;
    float fm = fmean[f * 256 + d];
    float v = 0.85f * gs[c * 256 + d] + 0.15f * fm;
    if (((c & 127) < 32) && (*step > 5)) v = 0.85f * v + 0.15f * gm;
    synced[c * 256 + d] = v;
    ncn[c * 256 + d] = 0.7f * v + 0.3f * ch[c * 256 + d];
    if (c < N_LOOP) {
        comb[c * 512 + d] = x[d];
        comb[c * 512 + 256 + d] = v;
    }
}

__global__ void k_ev1(const float* __restrict__ comb,
                      const float* __restrict__ eaW1, const float* __restrict__ eab1,
                      const float* __restrict__ egW1, const float* __restrict__ egb1,
                      float* __restrict__ h1ag) {
    int t = threadIdx.x, l = t & 63, w = t >> 6;
    int j = blockIdx.x * 4 + w;
    const float* W = (j < 128) ? (eaW1 + j * 512) : (egW1 + (j - 128) * 512);
    float bias = (j < 128) ? eab1[j] : egb1[j - 128];
    const float4* w4 = (const float4*)W;
    float4 wa = w4[l], wb = w4[64 + l];
    for (int i = 0; i < N_LOOP; ++i) {
        const float4* ci = (const float4*)(comb + i * 512);
        float4 va = ci[l], vb = ci[64 + l];
        float acc = wa.x*va.x + wa.y*va.y + wa.z*va.z + wa.w*va.w
                  + wb.x*vb.x + wb.y*vb.y + wb.z*vb.z + wb.w*vb.w;
        acc = wave_reduce64(acc);
        if (l == 0) h1ag[i * 256 + j] = fmaxf(acc + bias, 0.f);
    }
}

__global__ void k_ev2(const float* __restrict__ h1ag,
                      const float* __restrict__ eaW2, const float* __restrict__ eab2,
                      const float* __restrict__ egW2, const float* __restrict__ egb2,
                      float* __restrict__ outputs) {
    int t = threadIdx.x, l = t & 63, w = t >> 6;
    int tr = blockIdx.x * 4 + w;
    bool lo = (l < 32);
    int sl = l & 31;
    float4 wv = lo ? ((const float4*)(eaW2 + tr * 128))[sl]
                   : ((const float4*)(egW2 + tr * 128))[sl];
    float bias = eab2[tr] - egb2[tr];
    for (int i = 0; i < N_LOOP; ++i) {
        const float* hrow = h1ag + i * 256 + (lo ? 0 : 128);
        float4 v = *(const float4*)(hrow + sl * 4);
        float d_ = wv.x*v.x + wv.y*v.y + wv.z*v.z + wv.w*v.w;
        float acc = lo ? d_ : -d_;
        acc = wave_reduce64(acc);
        if (l == 0) outputs[i * 256 + tr] = acc + bias;
    }
}

__global__ void k_tension(const float* __restrict__ outputs, float* __restrict__ tensions) {
    __shared__ float red[256];
    int i = blockIdx.x, t = threadIdx.x;
    float o = outputs[i * 256 + t];
    red[t] = o * o;
    __syncthreads();
    for (int m = 128; m; m >>= 1) { if (t < m) red[t] += red[t + m]; __syncthreads(); }
    if (t == 0) tensions[i] = red[0] * (1.f / 256.f);
}

__global__ void k_gru(const float* __restrict__ outputs, const float* __restrict__ tensions,
                      const float* __restrict__ synced,
                      const float* __restrict__ Wih, const float* __restrict__ bih,
                      const float* __restrict__ Whh, const float* __restrict__ bhh,
                      float* __restrict__ rz, float* __restrict__ inb, float* __restrict__ hnb) {
    int t = threadIdx.x, l = t & 63, w = t >> 6;
    int u = blockIdx.x * 4 + w;
    const float* wr = Wih + (size_t)u * 257;
    float w0 = wr[4*l], w1 = wr[4*l+1], w2 = wr[4*l+2], w3 = wr[4*l+3];
    float wlast = wr[256];
    float4 wh = ((const float4*)(Whh + (size_t)u * 256))[l];
    float bg = bih[u], bh = bhh[u];
    bool isN = (u >= 512);
    for (int i = 0; i < N_LOOP; ++i) {
        const float* oi = outputs + i * 256 + 4 * l;
        const float* hi = synced + i * 256 + 4 * l;
        float ga = w0*oi[0] + w1*oi[1] + w2*oi[2] + w3*oi[3];
        float hh = wh.x*hi[0] + wh.y*hi[1] + wh.z*hi[2] + wh.w*hi[3];
        if (!isN) {
            float s = wave_reduce64(ga + hh);
            if (l == 0) rz[i * 512 + u] = s + bg + bh + wlast * tensions[i];
        } else {
            float sg2 = wave_reduce64(ga);
            float sh  = wave_reduce64(hh);
            if (l == 0) {
                inb[i * 256 + (u - 512)] = sg2 + bg + wlast * tensions[i];
                hnb[i * 256 + (u - 512)] = sh + bh;
            }
        }
    }
}

__global__ void k_gru_fin(const float* __restrict__ rz, const float* __restrict__ inb,
                          const float* __restrict__ hnb, const float* __restrict__ synced,
                          float* __restrict__ out) {
    int i = blockIdx.x, d = threadIdx.x;
    float r = 1.f / (1.f + expf(-rz[i * 512 + d]));
    float z = 1.f / (1.f + expf(-rz[i * 512 + 256 + d]));
    float nc = tanhf(inb[i * 256 + d] + r * hnb[i * 256 + d]);
    float H = synced[i * 256 + d];
    out[259 + i * 256 + d] = (1.f - z) * nc + z * H;
}

__global__ void k_combine(const float* __restrict__ outputs, const float* __restrict__ tensions,
                          float* __restrict__ out) {
    __shared__ float w[32];
    __shared__ float ts[32];
    int t = threadIdx.x;
    if (t < 32) ts[t] = tensions[t];
    __syncthreads();
    if (t == 0) {
        float mx = ts[0];
        for (int i = 1; i < 32; ++i) mx = fmaxf(mx, ts[i]);
        float s = 0.f, mean = 0.f;
        for (int i = 0; i < 32; ++i) { float e = expf(ts[i] - mx); w[i] = e; s += e; mean += ts[i]; }
        float inv = 1.f / s;
        for (int i = 0; i < 32; ++i) w[i] *= inv;
        out[256] = mean * (1.f / 32.f);
    }
    __syncthreads();
    float c = 0.f;
    for (int i = 0; i < 32; ++i) c += w[i] * outputs[i * 256 + t];
    out[t] = c;
}

extern "C" void kernel_launch(void* const* d_in, const int* in_sizes, int n_in,
                              void* d_out, int out_size, void* d_ws, size_t ws_size,
                              hipStream_t stream) {
    const float* x     = (const float*)d_in[0];
    const float* noise = (const float*)d_in[1];
    const float* ch    = (const float*)d_in[2];
    const float* gW1   = (const float*)d_in[3];
    const float* gb1   = (const float*)d_in[4];
    const float* gW2   = (const float*)d_in[5];
    const float* gb2   = (const float*)d_in[6];
    const float* gW3   = (const float*)d_in[7];
    const float* gb3   = (const float*)d_in[8];
    const float* dW1   = (const float*)d_in[9];
    const float* db1   = (const float*)d_in[10];
    const float* dW2   = (const float*)d_in[11];
    const float* db2   = (const float*)d_in[12];
    const float* dW3   = (const float*)d_in[13];
    const float* db3   = (const float*)d_in[14];
    const float* eaW1  = (const float*)d_in[15];
    const float* eab1  = (const float*)d_in[16];
    const float* eaW2  = (const float*)d_in[17];
    const float* eab2  = (const float*)d_in[18];
    const float* egW1  = (const float*)d_in[19];
    const float* egb1  = (const float*)d_in[20];
    const float* egW2  = (const float*)d_in[21];
    const float* egb2  = (const float*)d_in[22];
    const float* Wih   = (const float*)d_in[23];
    const float* bih   = (const float*)d_in[24];
    const float* Whh   = (const float*)d_in[25];
    const float* bhh   = (const float*)d_in[26];
    const int*   step  = (const int*)d_in[27];

    float* out = (float*)d_out;
    float* ws  = (float*)d_ws;
    float* h1buf    = ws;                 // 256
    float* h2       = h1buf + 256;        // 512
    float* gs       = h2 + 512;           // 262144
    float* fmean    = gs + 262144;        // 2048
    float* synced   = fmean + 2048;       // 262144
    float* ncn      = synced + 262144;    // 262144
    float* comb     = ncn + 262144;       // 16384
    float* h1ag     = comb + 16384;       // 8192
    float* outputs  = h1ag + 8192;        // 8192
    float* tensions = outputs + 8192;     // 32
    float* rz       = tensions + 32;      // 16384
    float* inb      = rz + 16384;         // 8192
    float* hnb      = inb + 8192;         // 8192
    float* d1r      = hnb + 8192;         // 512
    float* d1f      = d1r + 512;          // 512

    // --- generator head (cooperative; fallback to 2 kernels) ---
    {
        void* a[] = {(void*)&x, (void*)&noise, (void*)&gW1, (void*)&gb1,
                     (void*)&gW2, (void*)&gb2, (void*)&h1buf, (void*)&h2};
        hipError_t e = hipLaunchCooperativeKernel((const void*)k_gen_head,
                                                  dim3(128), dim3(256), a, 0, stream);
        if (e != hipSuccess) {
            k_gen_h1<<<64, 256, 0, stream>>>(x, noise, gW1, gb1, h1buf);
            k_gen_h2<<<128, 256, 0, stream>>>(h1buf, gW2, gb2, h2);
        }
    }

    k_gen_big<<<FLAT / 4, 256, 0, stream>>>(gW3, gb3, h2, gs);

    // --- small-op chain (cooperative; fallback to 8 kernels) ---
    {
        void* a[] = {(void*)&gs, (void*)&ch, (void*)&step, (void*)&x,
                     (void*)&eaW1, (void*)&eab1, (void*)&eaW2, (void*)&eab2,
                     (void*)&egW1, (void*)&egb1, (void*)&egW2, (void*)&egb2,
                     (void*)&Wih, (void*)&bih, (void*)&Whh, (void*)&bhh,
                     (void*)&fmean, (void*)&synced, (void*)&ncn, (void*)&comb,
                     (void*)&h1ag, (void*)&outputs, (void*)&tensions,
                     (void*)&rz, (void*)&inb, (void*)&hnb, (void*)&out};
        hipError_t e = hipLaunchCooperativeKernel((const void*)k_mega,
                                                  dim3(512), dim3(256), a, 0, stream);
        if (e != hipSuccess) {
            k_fmean<<<32, 256, 0, stream>>>(gs, fmean);
            k_sync<<<1024, 256, 0, stream>>>(gs, fmean, ch, step, x, synced, ncn, comb);
            k_ev1<<<64, 256, 0, stream>>>(comb, eaW1, eab1, egW1, egb1, h1ag);
            k_ev2<<<64, 256, 0, stream>>>(h1ag, eaW2, eab2, egW2, egb2, outputs);
            k_tension<<<32, 256, 0, stream>>>(outputs, tensions);
            k_gru<<<192, 256, 0, stream>>>(outputs, tensions, synced, Wih, bih, Whh, bhh, rz, inb, hnb);
            k_gru_fin<<<32, 256, 0, stream>>>(rz, inb, hnb, synced, out);
            k_combine<<<1, 256, 0, stream>>>(outputs, tensions, out);
        }
    }

    k_disc1<<<512, 1024, 0, stream>>>(dW1, db1, ncn, gs, d1r, d1f);
    k_disc_tail<<<2, 256, 0, stream>>>(dW2, db2, dW3, db3, d1r, d1f, out);
}

// Round 4
// 454.147 us; speedup vs baseline: 1.4420x; 1.4420x over previous
//
#include <hip/hip_runtime.h>
#include <math.h>

#define N_CELLS 1024
#define HID     256
#define IN_DIM  256
#define NOISE_DIM 32
#define OUT_DIM 256
#define N_LOOP  32
#define FLAT    (N_CELLS*HID)   // 262144

// fixed-point scale for deterministic faction-mean accumulation
#define FPSCALE 1099511627776.0   // 2^40

__device__ __forceinline__ float wave_reduce64(float v) {
    #pragma unroll
    for (int m = 32; m; m >>= 1) v += __shfl_xor(v, m);
    return v;
}

// ============ h1 = relu(W1.gi + b1)  (also zeros fmean accumulator) ============
__global__ void k_gen_h1(const float* __restrict__ x, const float* __restrict__ noise,
                         const float* __restrict__ W1, const float* __restrict__ b1,
                         float* __restrict__ h1, unsigned long long* __restrict__ fm_acc) {
    __shared__ __align__(16) float gi[288];
    int t = threadIdx.x, l = t & 63, w = t >> 6;
    int gid = blockIdx.x * 256 + t;
    if (gid < 2048) fm_acc[gid] = 0ULL;          // zero 8*256 fixed-point slots
    gi[t] = x[t];
    if (t < 32) gi[256 + t] = noise[t];
    __syncthreads();
    int j = blockIdx.x * 4 + w;                  // 256 rows, 64 blocks
    const float4* wr = (const float4*)(W1 + j * 288);
    const float4* g4 = (const float4*)gi;
    float4 a = wr[l], v = g4[l];
    float acc = a.x*v.x + a.y*v.y + a.z*v.z + a.w*v.w;
    if (l < 8) {
        float4 a2 = wr[64 + l], v2 = g4[64 + l];
        acc += a2.x*v2.x + a2.y*v2.y + a2.z*v2.z + a2.w*v2.w;
    }
    acc = wave_reduce64(acc);
    if (l == 0) h1[j] = fmaxf(acc + b1[j], 0.f);
}

// ============ h2 = relu(W2.h1 + b2), 512 rows ============
__global__ void k_gen_h2(const float* __restrict__ h1, const float* __restrict__ W2,
                         const float* __restrict__ b2, float* __restrict__ h2) {
    int t = threadIdx.x, l = t & 63, w = t >> 6;
    int j = blockIdx.x * 4 + w;
    float4 a = ((const float4*)(W2 + j * 256))[l];
    float4 v = ((const float4*)h1)[l];
    float acc = a.x*v.x + a.y*v.y + a.z*v.z + a.w*v.w;
    acc = wave_reduce64(acc);
    if (l == 0) h2[j] = fmaxf(acc + b2[j], 0.f);
}

// ============ gen_states = W3.h2 + b3 (wave per row) + fixed-point faction sums ============
__global__ void k_gen_big(const float* __restrict__ W3, const float* __restrict__ b3,
                          const float* __restrict__ h2, float* __restrict__ gs,
                          unsigned long long* __restrict__ fm_acc) {
    int lane = threadIdx.x & 63;
    int row  = blockIdx.x * (blockDim.x >> 6) + (threadIdx.x >> 6);
    const float4* h24 = (const float4*)h2;
    float4 ha = h24[lane], hb = h24[64 + lane];
    const float4* w4 = (const float4*)(W3 + (size_t)row * 512);
    float4 wa = w4[lane], wb = w4[64 + lane];
    float acc = wa.x*ha.x + wa.y*ha.y + wa.z*ha.z + wa.w*ha.w
              + wb.x*hb.x + wb.y*hb.y + wb.z*hb.z + wb.w*hb.w;
    acc = wave_reduce64(acc);
    if (lane == 0) {
        float val = acc + b3[row];
        gs[row] = val;
        // faction f = row>>15 (cell>>7), column d = row&255
        int slot = ((row >> 15) << 8) | (row & 255);
        long long q = llrint((double)val * FPSCALE);
        atomicAdd(fm_acc + slot, (unsigned long long)q);
    }
}

// ============ synced + new_cell_hiddens (reads fixed-point faction sums) ============
__global__ void k_sync(const float* __restrict__ gs,
                       const unsigned long long* __restrict__ fm_acc,
                       const float* __restrict__ ch, const int* __restrict__ step,
                       float* __restrict__ synced, float* __restrict__ ncn) {
    int c = blockIdx.x, d = threadIdx.x;
    int f = c >> 7;
    const float cvt = (float)(1.0 / (FPSCALE * 128.0));
    float gm = 0.f, fm = 0.f;
    #pragma unroll
    for (int k = 0; k < 8; ++k) {
        float v = (float)(long long)fm_acc[(k << 8) | d] * cvt;
        gm += v;
        if (k == f) fm = v;
    }
    gm *= 0.125f;
    float v = 0.85f * gs[c * 256 + d] + 0.15f * fm;
    if (((c & 127) < 32) && (*step > 5)) v = 0.85f * v + 0.15f * gm;
    synced[c * 256 + d] = v;
    ncn[c * 256 + d] = 0.7f * v + 0.3f * ch[c * 256 + d];
}

// ============ per-sample fused evaluator + GRU (block i = sample i) ============
__global__ void __launch_bounds__(256)
k_cell(const float* __restrict__ x, const float* __restrict__ synced,
       const float* __restrict__ eaW1, const float* __restrict__ eab1,
       const float* __restrict__ eaW2, const float* __restrict__ eab2,
       const float* __restrict__ egW1, const float* __restrict__ egb1,
       const float* __restrict__ egW2, const float* __restrict__ egb2,
       const float* __restrict__ Wih, const float* __restrict__ bih,
       const float* __restrict__ Whh, const float* __restrict__ bhh,
       float* __restrict__ outputs, float* __restrict__ tensions,
       float* __restrict__ out) {
    __shared__ __align__(16) float xh[512];     // [x | H]
    __shared__ __align__(16) float hag[256];    // [ha | hg]
    __shared__ __align__(16) float outs[256];
    __shared__ float red[256];
    __shared__ float tsh;
    int i = blockIdx.x, t = threadIdx.x;
    xh[t] = x[t];
    float Hd = synced[i * 256 + t];
    xh[256 + t] = Hd;
    __syncthreads();
    // --- ev layer 1: neuron t (t<128: ea, else eg), 512-dot ---
    {
        const float* W  = (t < 128) ? (eaW1 + t * 512) : (egW1 + (t - 128) * 512);
        float acc = (t < 128) ? eab1[t] : egb1[t - 128];
        const float4* w4 = (const float4*)W;
        const float4* v4 = (const float4*)xh;
        for (int k = 0; k < 128; ++k) {
            float4 w = w4[k], v = v4[k];
            acc += w.x*v.x + w.y*v.y + w.z*v.z + w.w*v.w;
        }
        hag[t] = fmaxf(acc, 0.f);
    }
    __syncthreads();
    // --- ev layer 2: output neuron t = a - g ---
    {
        float acc = eab2[t] - egb2[t];
        const float4* wa = (const float4*)(eaW2 + t * 128);
        const float4* wg = (const float4*)(egW2 + t * 128);
        const float4* h4a = (const float4*)hag;
        const float4* h4g = (const float4*)(hag + 128);
        for (int k = 0; k < 32; ++k) {
            float4 w = wa[k], v = h4a[k];
            acc += w.x*v.x + w.y*v.y + w.z*v.z + w.w*v.w;
            float4 w2 = wg[k], v2 = h4g[k];
            acc -= w2.x*v2.x + w2.y*v2.y + w2.z*v2.z + w2.w*v2.w;
        }
        outs[t] = acc;
        outputs[i * 256 + t] = acc;
        red[t] = acc * acc;
    }
    __syncthreads();
    for (int m = 128; m; m >>= 1) { if (t < m) red[t] += red[t + m]; __syncthreads(); }
    if (t == 0) { float tn = red[0] * (1.f / 256.f); tensions[i] = tn; tsh = tn; }
    __syncthreads();
    // --- GRU for dim t ---
    {
        float tn = tsh;
        float g[3], h[3];
        #pragma unroll
        for (int r = 0; r < 3; ++r) {
            int u = t + r * 256;
            const float* wr = Wih + (size_t)u * 257;   // rows are 1028B -> scalar loads
            float acc = bih[u];
            for (int k = 0; k < 256; ++k) acc += wr[k] * outs[k];
            acc += wr[256] * tn;
            g[r] = acc;
            const float4* wh = (const float4*)(Whh + (size_t)u * 256);
            const float4* H4 = (const float4*)(xh + 256);
            float acch = bhh[u];
            for (int k = 0; k < 64; ++k) {
                float4 w = wh[k], v = H4[k];
                acch += w.x*v.x + w.y*v.y + w.z*v.z + w.w*v.w;
            }
            h[r] = acch;
        }
        float r_ = 1.f / (1.f + expf(-(g[0] + h[0])));
        float z  = 1.f / (1.f + expf(-(g[1] + h[1])));
        float nc = tanhf(g[2] + r_ * h[2]);
        out[259 + i * 256 + t] = (1.f - z) * nc + z * Hd;
    }
}

// ============ fused disc layer-1 for real+fake (512 MB stream) ============
__global__ void k_disc1(const float* __restrict__ W1, const float* __restrict__ b1,
                        const float* __restrict__ real, const float* __restrict__ fake,
                        float* __restrict__ d1r, float* __restrict__ d1f) {
    __shared__ float sR[16];
    __shared__ float sF[16];
    int row = blockIdx.x, t = threadIdx.x, l = t & 63, w = t >> 6;
    const float4* w4 = (const float4*)(W1 + (size_t)row * FLAT);
    const float4* r4 = (const float4*)real;
    const float4* f4 = (const float4*)fake;
    float aR = 0.f, aF = 0.f;
    for (int i = t; i < FLAT / 4; i += 1024) {
        float4 ww = w4[i], r = r4[i], f = f4[i];
        aR += ww.x*r.x + ww.y*r.y + ww.z*r.z + ww.w*r.w;
        aF += ww.x*f.x + ww.y*f.y + ww.z*f.z + ww.w*f.w;
    }
    aR = wave_reduce64(aR);
    aF = wave_reduce64(aF);
    if (l == 0) { sR[w] = aR; sF[w] = aF; }
    __syncthreads();
    if (t < 16) {
        float r = sR[t], f = sF[t];
        #pragma unroll
        for (int m = 8; m; m >>= 1) { r += __shfl_xor(r, m); f += __shfl_xor(f, m); }
        if (t == 0) { d1r[row] = r + b1[row]; d1f[row] = f + b1[row]; }
    }
}

// ============ epilogue: blocks 0/1 = disc tail (real/fake), block 2 = combine ============
__global__ void k_epi(const float* __restrict__ W2, const float* __restrict__ b2,
                      const float* __restrict__ W3, const float* __restrict__ b3,
                      const float* __restrict__ d1r, const float* __restrict__ d1f,
                      const float* __restrict__ outputs, const float* __restrict__ tensions,
                      float* __restrict__ out) {
    int b = blockIdx.x, t = threadIdx.x;
    if (b < 2) {
        __shared__ __align__(16) float lv[512];
        __shared__ float l2[256];
        __shared__ float red[256];
        const float* d1 = b ? d1f : d1r;
        for (int j = t; j < 512; j += 256) { float v = d1[j]; lv[j] = v > 0.f ? v : 0.2f * v; }
        __syncthreads();
        {
            float acc = b2[t];
            const float4* wr = (const float4*)(W2 + t * 512);
            const float4* l4 = (const float4*)lv;
            for (int k = 0; k < 128; ++k) {
                float4 w = wr[k], v = l4[k];
                acc += w.x*v.x + w.y*v.y + w.z*v.z + w.w*v.w;
            }
            l2[t] = acc > 0.f ? acc : 0.2f * acc;
        }
        __syncthreads();
        red[t] = l2[t] * W3[t];
        __syncthreads();
        for (int m = 128; m; m >>= 1) { if (t < m) red[t] += red[t + m]; __syncthreads(); }
        if (t == 0) { float v = red[0] + b3[0]; out[257 + b] = 1.f / (1.f + expf(-v)); }
    } else {
        __shared__ float w[32];
        __shared__ float ts[32];
        if (t < 32) ts[t] = tensions[t];
        __syncthreads();
        if (t == 0) {
            float mx = ts[0];
            for (int i = 1; i < 32; ++i) mx = fmaxf(mx, ts[i]);
            float s = 0.f, mean = 0.f;
            for (int i = 0; i < 32; ++i) { float e = expf(ts[i] - mx); w[i] = e; s += e; mean += ts[i]; }
            float inv = 1.f / s;
            for (int i = 0; i < 32; ++i) w[i] *= inv;
            out[256] = mean * (1.f / 32.f);
        }
        __syncthreads();
        float c = 0.f;
        for (int i = 0; i < 32; ++i) c += w[i] * outputs[i * 256 + t];
        out[t] = c;
    }
}

extern "C" void kernel_launch(void* const* d_in, const int* in_sizes, int n_in,
                              void* d_out, int out_size, void* d_ws, size_t ws_size,
                              hipStream_t stream) {
    const float* x     = (const float*)d_in[0];
    const float* noise = (const float*)d_in[1];
    const float* ch    = (const float*)d_in[2];
    const float* gW1   = (const float*)d_in[3];
    const float* gb1   = (const float*)d_in[4];
    const float* gW2   = (const float*)d_in[5];
    const float* gb2   = (const float*)d_in[6];
    const float* gW3   = (const float*)d_in[7];
    const float* gb3   = (const float*)d_in[8];
    const float* dW1   = (const float*)d_in[9];
    const float* db1   = (const float*)d_in[10];
    const float* dW2   = (const float*)d_in[11];
    const float* db2   = (const float*)d_in[12];
    const float* dW3   = (const float*)d_in[13];
    const float* db3   = (const float*)d_in[14];
    const float* eaW1  = (const float*)d_in[15];
    const float* eab1  = (const float*)d_in[16];
    const float* eaW2  = (const float*)d_in[17];
    const float* eab2  = (const float*)d_in[18];
    const float* egW1  = (const float*)d_in[19];
    const float* egb1  = (const float*)d_in[20];
    const float* egW2  = (const float*)d_in[21];
    const float* egb2  = (const float*)d_in[22];
    const float* Wih   = (const float*)d_in[23];
    const float* bih   = (const float*)d_in[24];
    const float* Whh   = (const float*)d_in[25];
    const float* bhh   = (const float*)d_in[26];
    const int*   step  = (const int*)d_in[27];

    float* out = (float*)d_out;
    float* ws  = (float*)d_ws;
    float* h1buf    = ws;                 // 256
    float* h2       = h1buf + 256;        // 512
    float* gs       = h2 + 512;           // 262144
    float* synced   = gs + 262144;        // 262144
    float* ncn      = synced + 262144;    // 262144
    float* outputs  = ncn + 262144;       // 8192
    float* tensions = outputs + 8192;     // 32
    float* d1r      = tensions + 32;      // 512
    float* d1f      = d1r + 512;          // 512
    unsigned long long* fm_acc = (unsigned long long*)(d1f + 512); // 2048 ULL (8B-aligned)

    k_gen_h1<<<64, 256, 0, stream>>>(x, noise, gW1, gb1, h1buf, fm_acc);
    k_gen_h2<<<128, 256, 0, stream>>>(h1buf, gW2, gb2, h2);
    k_gen_big<<<FLAT / 4, 256, 0, stream>>>(gW3, gb3, h2, gs, fm_acc);
    k_sync<<<1024, 256, 0, stream>>>(gs, fm_acc, ch, step, synced, ncn);
    k_cell<<<32, 256, 0, stream>>>(x, synced, eaW1, eab1, eaW2, eab2,
                                   egW1, egb1, egW2, egb2,
                                   Wih, bih, Whh, bhh, outputs, tensions, out);
    k_disc1<<<512, 1024, 0, stream>>>(dW1, db1, ncn, gs, d1r, d1f);
    k_epi<<<3, 256, 0, stream>>>(dW2, db2, dW3, db3, d1r, d1f, outputs, tensions, out);
}

// Round 5
// 433.311 us; speedup vs baseline: 1.5113x; 1.0481x over previous
//
#include <hip/hip_runtime.h>
#include <math.h>

#define N_CELLS 1024
#define HID     256
#define IN_DIM  256
#define NOISE_DIM 32
#define OUT_DIM 256
#define N_LOOP  32
#define FLAT    (N_CELLS*HID)   // 262144

// fixed-point scale for deterministic faction-mean accumulation
#define FPSCALE 1099511627776.0   // 2^40

__device__ __forceinline__ float wave_reduce64(float v) {
    #pragma unroll
    for (int m = 32; m; m >>= 1) v += __shfl_xor(v, m);
    return v;
}

// ============ h1 = relu(W1.gi + b1)  (also zeros fmean accumulator) ============
__global__ void k_gen_h1(const float* __restrict__ x, const float* __restrict__ noise,
                         const float* __restrict__ W1, const float* __restrict__ b1,
                         float* __restrict__ h1, unsigned long long* __restrict__ fm_acc) {
    __shared__ __align__(16) float gi[288];
    int t = threadIdx.x, l = t & 63, w = t >> 6;
    int gid = blockIdx.x * 256 + t;
    if (gid < 2048) fm_acc[gid] = 0ULL;          // zero 8*256 fixed-point slots
    gi[t] = x[t];
    if (t < 32) gi[256 + t] = noise[t];
    __syncthreads();
    int j = blockIdx.x * 4 + w;                  // 256 rows, 64 blocks
    const float4* wr = (const float4*)(W1 + j * 288);
    const float4* g4 = (const float4*)gi;
    float4 a = wr[l], v = g4[l];
    float acc = a.x*v.x + a.y*v.y + a.z*v.z + a.w*v.w;
    if (l < 8) {
        float4 a2 = wr[64 + l], v2 = g4[64 + l];
        acc += a2.x*v2.x + a2.y*v2.y + a2.z*v2.z + a2.w*v2.w;
    }
    acc = wave_reduce64(acc);
    if (l == 0) h1[j] = fmaxf(acc + b1[j], 0.f);
}

// ============ h2 = relu(W2.h1 + b2), 512 rows ============
__global__ void k_gen_h2(const float* __restrict__ h1, const float* __restrict__ W2,
                         const float* __restrict__ b2, float* __restrict__ h2) {
    int t = threadIdx.x, l = t & 63, w = t >> 6;
    int j = blockIdx.x * 4 + w;
    float4 a = ((const float4*)(W2 + j * 256))[l];
    float4 v = ((const float4*)h1)[l];
    float acc = a.x*v.x + a.y*v.y + a.z*v.z + a.w*v.w;
    acc = wave_reduce64(acc);
    if (l == 0) h2[j] = fmaxf(acc + b2[j], 0.f);
}

// ============ gen_states = W3.h2 + b3 (wave per row) + fixed-point faction sums ============
__global__ void k_gen_big(const float* __restrict__ W3, const float* __restrict__ b3,
                          const float* __restrict__ h2, float* __restrict__ gs,
                          unsigned long long* __restrict__ fm_acc) {
    int lane = threadIdx.x & 63;
    int row  = blockIdx.x * (blockDim.x >> 6) + (threadIdx.x >> 6);
    const float4* h24 = (const float4*)h2;
    float4 ha = h24[lane], hb = h24[64 + lane];
    const float4* w4 = (const float4*)(W3 + (size_t)row * 512);
    float4 wa = w4[lane], wb = w4[64 + lane];
    float acc = wa.x*ha.x + wa.y*ha.y + wa.z*ha.z + wa.w*ha.w
              + wb.x*hb.x + wb.y*hb.y + wb.z*hb.z + wb.w*hb.w;
    acc = wave_reduce64(acc);
    if (lane == 0) {
        float val = acc + b3[row];
        gs[row] = val;
        int slot = ((row >> 15) << 8) | (row & 255);   // faction, column
        long long q = llrint((double)val * FPSCALE);
        atomicAdd(fm_acc + slot, (unsigned long long)q);
    }
}

// ============ ncn (all cells) + H rows (first 32 cells) ============
__global__ void k_sync(const float* __restrict__ gs,
                       const unsigned long long* __restrict__ fm_acc,
                       const float* __restrict__ ch, const int* __restrict__ step,
                       float* __restrict__ Hbuf, float* __restrict__ ncn) {
    int c = blockIdx.x, d = threadIdx.x;
    int f = c >> 7;
    const float cvt = (float)(1.0 / (FPSCALE * 128.0));
    float gm = 0.f, fm = 0.f;
    #pragma unroll
    for (int k = 0; k < 8; ++k) {
        float v = (float)(long long)fm_acc[(k << 8) | d] * cvt;
        gm += v;
        if (k == f) fm = v;
    }
    gm *= 0.125f;
    float v = 0.85f * gs[c * 256 + d] + 0.15f * fm;
    if (((c & 127) < 32) && (*step > 5)) v = 0.85f * v + 0.15f * gm;
    ncn[c * 256 + d] = 0.7f * v + 0.3f * ch[c * 256 + d];
    if (c < N_LOOP) Hbuf[c * 256 + d] = v;
}

// ============ MEGA: blocks 0..31 = per-sample eval+GRU chain, blocks 32..543 = disc1 rows ============
__global__ void __launch_bounds__(512)
k_mega(const float* __restrict__ dW1, const float* __restrict__ db1,
       const float* __restrict__ ncn, const float* __restrict__ gs,
       const float* __restrict__ x, const float* __restrict__ Hbuf,
       const float* __restrict__ eaW1, const float* __restrict__ eab1,
       const float* __restrict__ eaW2, const float* __restrict__ eab2,
       const float* __restrict__ egW1, const float* __restrict__ egb1,
       const float* __restrict__ egW2, const float* __restrict__ egb2,
       const float* __restrict__ Wih, const float* __restrict__ bih,
       const float* __restrict__ Whh, const float* __restrict__ bhh,
       float* __restrict__ d1r, float* __restrict__ d1f,
       float* __restrict__ outputs, float* __restrict__ tensions,
       float* __restrict__ out) {
    __shared__ float sR[8];
    __shared__ float sF[8];
    __shared__ __align__(16) float xh[512];      // [x | H]
    __shared__ __align__(16) float hag[256];     // [ha | hg]
    __shared__ __align__(16) float outs[256];
    __shared__ float red[256];
    __shared__ float rzA[512];                   // r,z pre-activations
    __shared__ float inb[256];
    __shared__ float hnb[256];
    __shared__ float tsh;
    int b = blockIdx.x, t = threadIdx.x, l = t & 63, w = t >> 6;

    if (b >= 32) {
        // ---------- disc1: one row of dW1 against real(ncn) and fake(gs) ----------
        int row = b - 32;
        const float4* w4 = (const float4*)(dW1 + (size_t)row * FLAT);
        const float4* r4 = (const float4*)ncn;
        const float4* f4 = (const float4*)gs;
        float aR = 0.f, aF = 0.f;
        for (int i = t; i < FLAT / 4; i += 512) {
            float4 ww = w4[i], r = r4[i], f = f4[i];
            aR += ww.x*r.x + ww.y*r.y + ww.z*r.z + ww.w*r.w;
            aF += ww.x*f.x + ww.y*f.y + ww.z*f.z + ww.w*f.w;
        }
        aR = wave_reduce64(aR);
        aF = wave_reduce64(aF);
        if (l == 0) { sR[w] = aR; sF[w] = aF; }
        __syncthreads();
        if (t < 8) {
            float r = sR[t], f = sF[t];
            #pragma unroll
            for (int m = 4; m; m >>= 1) { r += __shfl_xor(r, m); f += __shfl_xor(f, m); }
            if (t == 0) { d1r[row] = r + db1[row]; d1f[row] = f + db1[row]; }
        }
        return;
    }

    // ---------- per-sample chain, sample i = b ----------
    int i = b;
    if (t < 256) { xh[t] = x[t]; xh[256 + t] = Hbuf[i * 256 + t]; }
    __syncthreads();

    // ev layer 1: 8 waves x 32 neurons, wave-per-row 512-dot
    for (int k = 0; k < 32; ++k) {
        int j = w * 32 + k;
        const float* W = (j < 128) ? (eaW1 + (size_t)j * 512) : (egW1 + (size_t)(j - 128) * 512);
        const float4* w4 = (const float4*)W;
        const float4* v4 = (const float4*)xh;
        float4 a = w4[l], v = v4[l];
        float acc = a.x*v.x + a.y*v.y + a.z*v.z + a.w*v.w;
        float4 a2 = w4[64 + l], v2 = v4[64 + l];
        acc += a2.x*v2.x + a2.y*v2.y + a2.z*v2.z + a2.w*v2.w;
        acc = wave_reduce64(acc);
        if (l == 0) {
            float bias = (j < 128) ? eab1[j] : egb1[j - 128];
            hag[j] = fmaxf(acc + bias, 0.f);
        }
    }
    __syncthreads();

    // ev layer 2: 8 waves x 32 neurons; lanes 0-31 ea, 32-63 eg (signed reduce => a-g)
    for (int k = 0; k < 32; ++k) {
        int tr = w * 32 + k;
        int sl = l & 31;
        bool lo = (l < 32);
        const float4* wv4 = lo ? (const float4*)(eaW2 + (size_t)tr * 128)
                               : (const float4*)(egW2 + (size_t)tr * 128);
        const float4* h4 = (const float4*)(hag + (lo ? 0 : 128));
        float4 a = wv4[sl], v = h4[sl];
        float d_ = a.x*v.x + a.y*v.y + a.z*v.z + a.w*v.w;
        float acc = lo ? d_ : -d_;
        acc = wave_reduce64(acc);
        if (l == 0) {
            float o = acc + eab2[tr] - egb2[tr];
            outs[tr] = o;
            outputs[i * 256 + tr] = o;
        }
    }
    __syncthreads();

    // tension
    if (t < 256) red[t] = outs[t] * outs[t];
    __syncthreads();
    for (int m = 128; m; m >>= 1) { if (t < m) red[t] += red[t + m]; __syncthreads(); }
    if (t == 0) { float tn = red[0] * (1.f / 256.f); tensions[i] = tn; tsh = tn; }
    __syncthreads();
    float tn = tsh;

    // GRU matvecs: 8 waves x 96 rows (768 rows)
    {
        float4 ov = ((const float4*)outs)[l];
        float4 Hv = ((const float4*)(xh + 256))[l];
        for (int k = 0; k < 96; ++k) {
            int u = w * 96 + k;
            const float* wr = Wih + (size_t)u * 257;   // 257-row: scalar (still coalesced)
            float g0 = wr[4*l]*ov.x + wr[4*l+1]*ov.y + wr[4*l+2]*ov.z + wr[4*l+3]*ov.w;
            if (l == 0) g0 += wr[256] * tn;
            float4 wh = ((const float4*)(Whh + (size_t)u * 256))[l];
            float h0 = wh.x*Hv.x + wh.y*Hv.y + wh.z*Hv.z + wh.w*Hv.w;
            if (u < 512) {
                float s = wave_reduce64(g0 + h0);
                if (l == 0) rzA[u] = s + bih[u] + bhh[u];
            } else {
                float sg = wave_reduce64(g0);
                float sh = wave_reduce64(h0);
                if (l == 0) { inb[u - 512] = sg + bih[u]; hnb[u - 512] = sh + bhh[u]; }
            }
        }
    }
    __syncthreads();

    // GRU finish
    if (t < 256) {
        float r = 1.f / (1.f + expf(-rzA[t]));
        float z = 1.f / (1.f + expf(-rzA[256 + t]));
        float nc = tanhf(inb[t] + r * hnb[t]);
        float Hd = xh[256 + t];
        out[259 + i * 256 + t] = (1.f - z) * nc + z * Hd;
    }
}

// ============ epilogue: blocks 0/1 = disc tail (real/fake), block 2 = combine ============
__global__ void k_epi(const float* __restrict__ W2, const float* __restrict__ b2,
                      const float* __restrict__ W3, const float* __restrict__ b3,
                      const float* __restrict__ d1r, const float* __restrict__ d1f,
                      const float* __restrict__ outputs, const float* __restrict__ tensions,
                      float* __restrict__ out) {
    int b = blockIdx.x, t = threadIdx.x;
    if (b < 2) {
        __shared__ __align__(16) float lv[512];
        __shared__ float l2[256];
        __shared__ float red[256];
        const float* d1 = b ? d1f : d1r;
        for (int j = t; j < 512; j += 256) { float v = d1[j]; lv[j] = v > 0.f ? v : 0.2f * v; }
        __syncthreads();
        {
            float acc = b2[t];
            const float4* wr = (const float4*)(W2 + t * 512);
            const float4* l4 = (const float4*)lv;
            for (int k = 0; k < 128; ++k) {
                float4 w = wr[k], v = l4[k];
                acc += w.x*v.x + w.y*v.y + w.z*v.z + w.w*v.w;
            }
            l2[t] = acc > 0.f ? acc : 0.2f * acc;
        }
        __syncthreads();
        red[t] = l2[t] * W3[t];
        __syncthreads();
        for (int m = 128; m; m >>= 1) { if (t < m) red[t] += red[t + m]; __syncthreads(); }
        if (t == 0) { float v = red[0] + b3[0]; out[257 + b] = 1.f / (1.f + expf(-v)); }
    } else {
        __shared__ float w[32];
        __shared__ float ts[32];
        if (t < 32) ts[t] = tensions[t];
        __syncthreads();
        if (t == 0) {
            float mx = ts[0];
            for (int i = 1; i < 32; ++i) mx = fmaxf(mx, ts[i]);
            float s = 0.f, mean = 0.f;
            for (int i = 0; i < 32; ++i) { float e = expf(ts[i] - mx); w[i] = e; s += e; mean += ts[i]; }
            float inv = 1.f / s;
            for (int i = 0; i < 32; ++i) w[i] *= inv;
            out[256] = mean * (1.f / 32.f);
        }
        __syncthreads();
        float c = 0.f;
        for (int i = 0; i < 32; ++i) c += w[i] * outputs[i * 256 + t];
        out[t] = c;
    }
}

extern "C" void kernel_launch(void* const* d_in, const int* in_sizes, int n_in,
                              void* d_out, int out_size, void* d_ws, size_t ws_size,
                              hipStream_t stream) {
    const float* x     = (const float*)d_in[0];
    const float* noise = (const float*)d_in[1];
    const float* ch    = (const float*)d_in[2];
    const float* gW1   = (const float*)d_in[3];
    const float* gb1   = (const float*)d_in[4];
    const float* gW2   = (const float*)d_in[5];
    const float* gb2   = (const float*)d_in[6];
    const float* gW3   = (const float*)d_in[7];
    const float* gb3   = (const float*)d_in[8];
    const float* dW1   = (const float*)d_in[9];
    const float* db1   = (const float*)d_in[10];
    const float* dW2   = (const float*)d_in[11];
    const float* db2   = (const float*)d_in[12];
    const float* dW3   = (const float*)d_in[13];
    const float* db3   = (const float*)d_in[14];
    const float* eaW1  = (const float*)d_in[15];
    const float* eab1  = (const float*)d_in[16];
    const float* eaW2  = (const float*)d_in[17];
    const float* eab2  = (const float*)d_in[18];
    const float* egW1  = (const float*)d_in[19];
    const float* egb1  = (const float*)d_in[20];
    const float* egW2  = (const float*)d_in[21];
    const float* egb2  = (const float*)d_in[22];
    const float* Wih   = (const float*)d_in[23];
    const float* bih   = (const float*)d_in[24];
    const float* Whh   = (const float*)d_in[25];
    const float* bhh   = (const float*)d_in[26];
    const int*   step  = (const int*)d_in[27];

    float* out = (float*)d_out;
    float* ws  = (float*)d_ws;
    float* h1buf    = ws;                 // 256
    float* h2       = h1buf + 256;        // 512
    float* gs       = h2 + 512;           // 262144
    float* ncn      = gs + 262144;        // 262144
    float* Hbuf     = ncn + 262144;       // 8192
    float* outputs  = Hbuf + 8192;        // 8192
    float* tensions = outputs + 8192;     // 32
    float* d1r      = tensions + 32;      // 512
    float* d1f      = d1r + 512;          // 512
    unsigned long long* fm_acc = (unsigned long long*)(d1f + 512); // 2048 ULL

    k_gen_h1<<<64, 256, 0, stream>>>(x, noise, gW1, gb1, h1buf, fm_acc);
    k_gen_h2<<<128, 256, 0, stream>>>(h1buf, gW2, gb2, h2);
    k_gen_big<<<FLAT / 4, 256, 0, stream>>>(gW3, gb3, h2, gs, fm_acc);
    k_sync<<<1024, 256, 0, stream>>>(gs, fm_acc, ch, step, Hbuf, ncn);
    k_mega<<<544, 512, 0, stream>>>(dW1, db1, ncn, gs, x, Hbuf,
                                    eaW1, eab1, eaW2, eab2,
                                    egW1, egb1, egW2, egb2,
                                    Wih, bih, Whh, bhh,
                                    d1r, d1f, outputs, tensions, out);
    k_epi<<<3, 256, 0, stream>>>(dW2, db2, dW3, db3, d1r, d1f, outputs, tensions, out);
}

// Round 6
// 292.556 us; speedup vs baseline: 2.2384x; 1.4811x over previous
//
#include <hip/hip_runtime.h>
#include <math.h>

#define N_CELLS 1024
#define HID     256
#define IN_DIM  256
#define NOISE_DIM 32
#define OUT_DIM 256
#define N_LOOP  32
#define FLAT    (N_CELLS*HID)   // 262144

__device__ __forceinline__ float wave_reduce64(float v) {
    #pragma unroll
    for (int m = 32; m; m >>= 1) v += __shfl_xor(v, m);
    return v;
}

// ============ h1 = relu(W1.gi + b1), wave-per-row (256 rows x 288) ============
__global__ void k_gen_h1(const float* __restrict__ x, const float* __restrict__ noise,
                         const float* __restrict__ W1, const float* __restrict__ b1,
                         float* __restrict__ h1) {
    __shared__ __align__(16) float gi[288];
    int t = threadIdx.x, l = t & 63, w = t >> 6;
    gi[t] = x[t];
    if (t < 32) gi[256 + t] = noise[t];
    __syncthreads();
    int j = blockIdx.x * 4 + w;
    const float4* wr = (const float4*)(W1 + j * 288);
    const float4* g4 = (const float4*)gi;
    float4 a = wr[l], v = g4[l];
    float acc = a.x*v.x + a.y*v.y + a.z*v.z + a.w*v.w;
    if (l < 8) {
        float4 a2 = wr[64 + l], v2 = g4[64 + l];
        acc += a2.x*v2.x + a2.y*v2.y + a2.z*v2.z + a2.w*v2.w;
    }
    acc = wave_reduce64(acc);
    if (l == 0) h1[j] = fmaxf(acc + b1[j], 0.f);
}

// ============ h2 = relu(W2.h1 + b2), wave-per-row (512 rows x 256) ============
__global__ void k_gen_h2(const float* __restrict__ h1, const float* __restrict__ W2,
                         const float* __restrict__ b2, float* __restrict__ h2) {
    int t = threadIdx.x, l = t & 63, w = t >> 6;
    int j = blockIdx.x * 4 + w;
    float4 a = ((const float4*)(W2 + j * 256))[l];
    float4 v = ((const float4*)h1)[l];
    float acc = a.x*v.x + a.y*v.y + a.z*v.z + a.w*v.w;
    acc = wave_reduce64(acc);
    if (l == 0) h2[j] = fmaxf(acc + b2[j], 0.f);
}

// ============ gen_states = W3.h2 + b3 (wave per row) ============
__global__ void k_gen_big(const float* __restrict__ W3, const float* __restrict__ b3,
                          const float* __restrict__ h2, float* __restrict__ gs) {
    int lane = threadIdx.x & 63;
    int row  = blockIdx.x * (blockDim.x >> 6) + (threadIdx.x >> 6);
    const float4* h24 = (const float4*)h2;
    float4 ha = h24[lane], hb = h24[64 + lane];
    const float4* w4 = (const float4*)(W3 + (size_t)row * 512);
    float4 wa = w4[lane], wb = w4[64 + lane];
    float acc = wa.x*ha.x + wa.y*ha.y + wa.z*ha.z + wa.w*ha.w
              + wb.x*hb.x + wb.y*hb.y + wb.z*hb.z + wb.w*hb.w;
    acc = wave_reduce64(acc);
    if (lane == 0) gs[row] = acc + b3[row];
}

// ============ per-faction column means (proven r2 version) ============
__global__ void k_fmean(const float* __restrict__ gs, float* __restrict__ fmean) {
    __shared__ float part[4][64];
    int b = blockIdx.x, t = threadIdx.x;
    int f = b >> 2, q = b & 3;
    int c = q * 64 + (t & 63), rg = t >> 6;
    const float* base = gs + (size_t)(f * 128 + rg * 32) * 256 + c;
    float s = 0.f;
    for (int i = 0; i < 32; ++i) s += base[(size_t)i * 256];
    part[rg][t & 63] = s;
    __syncthreads();
    if (t < 64) {
        float v = part[0][t] + part[1][t] + part[2][t] + part[3][t];
        fmean[f * 256 + q * 64 + t] = v * (1.f / 128.f);
    }
}

// ============ ncn (all cells) + H rows (first 32 cells) ============
__global__ void k_sync(const float* __restrict__ gs, const float* __restrict__ fmean,
                       const float* __restrict__ ch, const int* __restrict__ step,
                       float* __restrict__ Hbuf, float* __restrict__ ncn) {
    int c = blockIdx.x, d = threadIdx.x;
    int f = c >> 7;
    float gm = 0.f;
    #pragma unroll
    for (int k = 0; k < 8; ++k) gm += fmean[k * 256 + d];
    gm *= 0.125f;
    float fm = fmean[f * 256 + d];
    float v = 0.85f * gs[c * 256 + d] + 0.15f * fm;
    if (((c & 127) < 32) && (*step > 5)) v = 0.85f * v + 0.15f * gm;
    ncn[c * 256 + d] = 0.7f * v + 0.3f * ch[c * 256 + d];
    if (c < N_LOOP) Hbuf[c * 256 + d] = v;
}

// ============ MEGA (1024 thr): blocks 0..31 = per-sample eval+GRU chain,
//                               blocks 32..543 = disc1 rows ============
__global__ void k_mega(const float* __restrict__ dW1, const float* __restrict__ db1,
                       const float* __restrict__ ncn, const float* __restrict__ gs,
                       const float* __restrict__ x, const float* __restrict__ Hbuf,
                       const float* __restrict__ eaW1, const float* __restrict__ eab1,
                       const float* __restrict__ eaW2, const float* __restrict__ eab2,
                       const float* __restrict__ egW1, const float* __restrict__ egb1,
                       const float* __restrict__ egW2, const float* __restrict__ egb2,
                       const float* __restrict__ Wih, const float* __restrict__ bih,
                       const float* __restrict__ Whh, const float* __restrict__ bhh,
                       float* __restrict__ d1r, float* __restrict__ d1f,
                       float* __restrict__ outputs, float* __restrict__ tensions,
                       float* __restrict__ out) {
    __shared__ float sR[16];
    __shared__ float sF[16];
    __shared__ __align__(16) float xh[512];      // [x | H]
    __shared__ __align__(16) float hag[256];     // [ha | hg]
    __shared__ __align__(16) float outs[256];
    __shared__ float red[256];
    __shared__ float rzA[512];
    __shared__ float inb[256];
    __shared__ float hnb[256];
    __shared__ float tsh;
    int b = blockIdx.x, t = threadIdx.x, l = t & 63, w = t >> 6;

    if (b >= 32) {
        // ---------- disc1: one row of dW1 vs real(ncn) and fake(gs) ----------
        int row = b - 32;
        const float4* w4 = (const float4*)(dW1 + (size_t)row * FLAT);
        const float4* r4 = (const float4*)ncn;
        const float4* f4 = (const float4*)gs;
        float aR = 0.f, aF = 0.f;
        for (int i = t; i < FLAT / 4; i += 1024) {
            float4 ww = w4[i], r = r4[i], f = f4[i];
            aR += ww.x*r.x + ww.y*r.y + ww.z*r.z + ww.w*r.w;
            aF += ww.x*f.x + ww.y*f.y + ww.z*f.z + ww.w*f.w;
        }
        aR = wave_reduce64(aR);
        aF = wave_reduce64(aF);
        if (l == 0) { sR[w] = aR; sF[w] = aF; }
        __syncthreads();
        if (t < 16) {
            float r = sR[t], f = sF[t];
            #pragma unroll
            for (int m = 8; m; m >>= 1) { r += __shfl_xor(r, m); f += __shfl_xor(f, m); }
            if (t == 0) { d1r[row] = r + db1[row]; d1f[row] = f + db1[row]; }
        }
        return;
    }

    // ---------- per-sample chain, sample i = b (16 waves) ----------
    int i = b;
    if (t < 512) xh[t] = (t < 256) ? x[t] : Hbuf[i * 256 + (t - 256)];
    __syncthreads();

    // ev layer 1: 16 waves x 16 neurons, wave-per-row 512-dot
    for (int k = 0; k < 16; ++k) {
        int j = w * 16 + k;
        const float* W = (j < 128) ? (eaW1 + (size_t)j * 512) : (egW1 + (size_t)(j - 128) * 512);
        const float4* w4 = (const float4*)W;
        const float4* v4 = (const float4*)xh;
        float4 a = w4[l], v = v4[l];
        float acc = a.x*v.x + a.y*v.y + a.z*v.z + a.w*v.w;
        float4 a2 = w4[64 + l], v2 = v4[64 + l];
        acc += a2.x*v2.x + a2.y*v2.y + a2.z*v2.z + a2.w*v2.w;
        acc = wave_reduce64(acc);
        if (l == 0) {
            float bias = (j < 128) ? eab1[j] : egb1[j - 128];
            hag[j] = fmaxf(acc + bias, 0.f);
        }
    }
    __syncthreads();

    // ev layer 2: 16 waves x 16 neurons; lanes 0-31 ea(+), 32-63 eg(-)
    for (int k = 0; k < 16; ++k) {
        int tr = w * 16 + k;
        int sl = l & 31;
        bool lo = (l < 32);
        const float4* wv4 = lo ? (const float4*)(eaW2 + (size_t)tr * 128)
                               : (const float4*)(egW2 + (size_t)tr * 128);
        const float4* h4 = (const float4*)(hag + (lo ? 0 : 128));
        float4 a = wv4[sl], v = h4[sl];
        float d_ = a.x*v.x + a.y*v.y + a.z*v.z + a.w*v.w;
        float acc = lo ? d_ : -d_;
        acc = wave_reduce64(acc);
        if (l == 0) {
            float o = acc + eab2[tr] - egb2[tr];
            outs[tr] = o;
            outputs[i * 256 + tr] = o;
        }
    }
    __syncthreads();

    // tension
    if (t < 256) red[t] = outs[t] * outs[t];
    __syncthreads();
    for (int m = 128; m; m >>= 1) { if (t < m && t + m < 256) red[t] += red[t + m]; __syncthreads(); }
    if (t == 0) { float tn = red[0] * (1.f / 256.f); tensions[i] = tn; tsh = tn; }
    __syncthreads();
    float tn = tsh;

    // GRU matvecs: 16 waves x 48 rows (768 rows)
    {
        float4 ov = ((const float4*)outs)[l];
        float4 Hv = ((const float4*)(xh + 256))[l];
        for (int k = 0; k < 48; ++k) {
            int u = w * 48 + k;
            const float* wr = Wih + (size_t)u * 257;
            float g0 = wr[4*l]*ov.x + wr[4*l+1]*ov.y + wr[4*l+2]*ov.z + wr[4*l+3]*ov.w;
            if (l == 0) g0 += wr[256] * tn;
            float4 wh = ((const float4*)(Whh + (size_t)u * 256))[l];
            float h0 = wh.x*Hv.x + wh.y*Hv.y + wh.z*Hv.z + wh.w*Hv.w;
            if (u < 512) {
                float s = wave_reduce64(g0 + h0);
                if (l == 0) rzA[u] = s + bih[u] + bhh[u];
            } else {
                float sg = wave_reduce64(g0);
                float sh = wave_reduce64(h0);
                if (l == 0) { inb[u - 512] = sg + bih[u]; hnb[u - 512] = sh + bhh[u]; }
            }
        }
    }
    __syncthreads();

    // GRU finish
    if (t < 256) {
        float r = 1.f / (1.f + expf(-rzA[t]));
        float z = 1.f / (1.f + expf(-rzA[256 + t]));
        float nc = tanhf(inb[t] + r * hnb[t]);
        float Hd = xh[256 + t];
        out[259 + i * 256 + t] = (1.f - z) * nc + z * Hd;
    }
}

// ============ epilogue: blocks 0/1 = disc tail (real/fake), block 2 = combine ============
__global__ void k_epi(const float* __restrict__ W2, const float* __restrict__ b2,
                      const float* __restrict__ W3, const float* __restrict__ b3,
                      const float* __restrict__ d1r, const float* __restrict__ d1f,
                      const float* __restrict__ outputs, const float* __restrict__ tensions,
                      float* __restrict__ out) {
    int b = blockIdx.x, t = threadIdx.x;
    if (b < 2) {
        __shared__ __align__(16) float lv[512];
        __shared__ float l2[256];
        __shared__ float red[256];
        const float* d1 = b ? d1f : d1r;
        for (int j = t; j < 512; j += 256) { float v = d1[j]; lv[j] = v > 0.f ? v : 0.2f * v; }
        __syncthreads();
        {
            float acc = b2[t];
            const float4* wr = (const float4*)(W2 + t * 512);
            const float4* l4 = (const float4*)lv;
            for (int k = 0; k < 128; ++k) {
                float4 w = wr[k], v = l4[k];
                acc += w.x*v.x + w.y*v.y + w.z*v.z + w.w*v.w;
            }
            l2[t] = acc > 0.f ? acc : 0.2f * acc;
        }
        __syncthreads();
        red[t] = l2[t] * W3[t];
        __syncthreads();
        for (int m = 128; m; m >>= 1) { if (t < m) red[t] += red[t + m]; __syncthreads(); }
        if (t == 0) { float v = red[0] + b3[0]; out[257 + b] = 1.f / (1.f + expf(-v)); }
    } else {
        __shared__ float w[32];
        __shared__ float ts[32];
        if (t < 32) ts[t] = tensions[t];
        __syncthreads();
        if (t == 0) {
            float mx = ts[0];
            for (int i = 1; i < 32; ++i) mx = fmaxf(mx, ts[i]);
            float s = 0.f, mean = 0.f;
            for (int i = 0; i < 32; ++i) { float e = expf(ts[i] - mx); w[i] = e; s += e; mean += ts[i]; }
            float inv = 1.f / s;
            for (int i = 0; i < 32; ++i) w[i] *= inv;
            out[256] = mean * (1.f / 32.f);
        }
        __syncthreads();
        float c = 0.f;
        for (int i = 0; i < 32; ++i) c += w[i] * outputs[i * 256 + t];
        out[t] = c;
    }
}

extern "C" void kernel_launch(void* const* d_in, const int* in_sizes, int n_in,
                              void* d_out, int out_size, void* d_ws, size_t ws_size,
                              hipStream_t stream) {
    const float* x     = (const float*)d_in[0];
    const float* noise = (const float*)d_in[1];
    const float* ch    = (const float*)d_in[2];
    const float* gW1   = (const float*)d_in[3];
    const float* gb1   = (const float*)d_in[4];
    const float* gW2   = (const float*)d_in[5];
    const float* gb2   = (const float*)d_in[6];
    const float* gW3   = (const float*)d_in[7];
    const float* gb3   = (const float*)d_in[8];
    const float* dW1   = (const float*)d_in[9];
    const float* db1   = (const float*)d_in[10];
    const float* dW2   = (const float*)d_in[11];
    const float* db2   = (const float*)d_in[12];
    const float* dW3   = (const float*)d_in[13];
    const float* db3   = (const float*)d_in[14];
    const float* eaW1  = (const float*)d_in[15];
    const float* eab1  = (const float*)d_in[16];
    const float* eaW2  = (const float*)d_in[17];
    const float* eab2  = (const float*)d_in[18];
    const float* egW1  = (const float*)d_in[19];
    const float* egb1  = (const float*)d_in[20];
    const float* egW2  = (const float*)d_in[21];
    const float* egb2  = (const float*)d_in[22];
    const float* Wih   = (const float*)d_in[23];
    const float* bih   = (const float*)d_in[24];
    const float* Whh   = (const float*)d_in[25];
    const float* bhh   = (const float*)d_in[26];
    const int*   step  = (const int*)d_in[27];

    float* out = (float*)d_out;
    float* ws  = (float*)d_ws;
    float* h1buf    = ws;                 // 256
    float* h2       = h1buf + 256;        // 512
    float* gs       = h2 + 512;           // 262144
    float* ncn      = gs + 262144;        // 262144
    float* fmean    = ncn + 262144;       // 2048
    float* Hbuf     = fmean + 2048;       // 8192
    float* outputs  = Hbuf + 8192;        // 8192
    float* tensions = outputs + 8192;     // 32
    float* d1r      = tensions + 32;      // 512
    float* d1f      = d1r + 512;          // 512

    k_gen_h1<<<64, 256, 0, stream>>>(x, noise, gW1, gb1, h1buf);
    k_gen_h2<<<128, 256, 0, stream>>>(h1buf, gW2, gb2, h2);
    k_gen_big<<<FLAT / 4, 256, 0, stream>>>(gW3, gb3, h2, gs);
    k_fmean<<<32, 256, 0, stream>>>(gs, fmean);
    k_sync<<<1024, 256, 0, stream>>>(gs, fmean, ch, step, Hbuf, ncn);
    k_mega<<<544, 1024, 0, stream>>>(dW1, db1, ncn, gs, x, Hbuf,
                                     eaW1, eab1, eaW2, eab2,
                                     egW1, egb1, egW2, egb2,
                                     Wih, bih, Whh, bhh,
                                     d1r, d1f, outputs, tensions, out);
    k_epi<<<3, 256, 0, stream>>>(dW2, db2, dW3, db3, d1r, d1f, outputs, tensions, out);
}